// Round 1
// baseline (189.652 us; speedup 1.0000x reference)
//
#include <hip/hip_runtime.h>

// QNStepTD: n-step TD loss.
//   target[b] = sum_{t<T} gamma^t*reward[t,b] + gamma^T*next_n_q[b,na[b]]*(1-done[b])
//   td[b]     = (q[b,a[b]] - target[b])^2 ; loss = mean(td*weight)
// d_out layout: [loss, td[0..B-1]]
//
// R3: block-wide 512-row LDS tiles fixed the divergent gathers (R1/R2) but
// floored at ~62us with VALUBusy 2%, HBM 1.4TB/s, occupancy 33% -- latency
// bound: two vmcnt(0)+barrier drains per block and 32.5KB LDS (4 blocks/CU).
// R4: per-WAVE 4KB LDS slices, zero staging barriers. Each wave stages its
// own 64 q-rows + 64 nq-rows (coalesced float4) into a private slice and
// gathers with plain ds_read (same-wave ordering, no __syncthreads). All
// global loads issued up front => ~8.5KB in flight per wave from cycle 0.
// LDS 16KB/block -> 8 blocks/CU -> 32 waves/CU.

#define BLOCK 256

__global__ __launch_bounds__(BLOCK) void qnstep_td_main(
    const float* __restrict__ q,
    const float* __restrict__ nq,
    const int*   __restrict__ act,
    const int*   __restrict__ nact,
    const float* __restrict__ rew,
    const int*   __restrict__ done,
    const float* __restrict__ w,
    const float* __restrict__ gamma_p,
    float*       __restrict__ out,      // out[1..B] = td
    float*       __restrict__ partial,  // per-block sums (d_ws)
    int B, int T)
{
    // fast path assumes N==16 (row == 64B == 4 float4) and B % BLOCK == 0
    __shared__ float tile[4][64 * 16];          // 16 KB: one 4 KB slice per wave

    const int tid  = threadIdx.x;
    const int wave = tid >> 6, lane = tid & 63;
    const long long b  = (long long)blockIdx.x * BLOCK + tid;   // this thread's sample
    const long long r0 = b - lane;                              // wave's first row
    const float gamma = gamma_p[0];

    // ---- issue ALL global loads up front (max MLP, nothing waits yet) ----
    const float4* q4  = (const float4*)q  + r0 * 4;   // 64 rows * 4 float4
    const float4* nq4 = (const float4*)nq + r0 * 4;
    const float4 qr0 = q4[lane];
    const float4 qr1 = q4[lane + 64];
    const float4 qr2 = q4[lane + 128];
    const float4 qr3 = q4[lane + 192];
    const float4 nr0 = nq4[lane];
    const float4 nr1 = nq4[lane + 64];
    const float4 nr2 = nq4[lane + 128];
    const float4 nr3 = nq4[lane + 192];

    const int   a  = act[b];
    const int   na = nact[b];
    const int   dn = done[b];
    const float wt = w[b];

    float tgt = 0.f, f = 1.0f;
    #pragma unroll 8
    for (int t = 0; t < T; ++t) {
        tgt += f * rew[(long long)t * B + b];
        f *= gamma;
    }
    // f == gamma^T

    float*  sl  = tile[wave];
    float4* sl4 = (float4*)sl;

    // ---- q: per-wave stage + gather (same-wave dep only, no barrier) ----
    sl4[lane]       = qr0;
    sl4[lane + 64]  = qr1;
    sl4[lane + 128] = qr2;
    sl4[lane + 192] = qr3;
    const float qsa = sl[lane * 16 + a];        // row `lane` of this wave

    // ---- nq: reuse the slice (WAR ordered by in-order per-wave DS pipe) ----
    sl4[lane]       = nr0;
    sl4[lane + 64]  = nr1;
    sl4[lane + 128] = nr2;
    sl4[lane + 192] = nr3;
    const float nqsa = sl[lane * 16 + na];

    // ---- target, td, store ----
    tgt += f * nqsa * (dn ? 0.f : 1.f);
    const float e  = qsa - tgt;
    const float td = e * e;
    out[1 + b] = td;

    float val = td * wt;

    // ---- block reduction -> partial[blk] (only barrier in the kernel) ----
    #pragma unroll
    for (int off = 32; off > 0; off >>= 1)
        val += __shfl_down(val, off, 64);

    __shared__ float ssum[BLOCK / 64];
    if (lane == 0) ssum[wave] = val;
    __syncthreads();
    if (tid == 0)
        partial[blockIdx.x] = ssum[0] + ssum[1] + ssum[2] + ssum[3];
}

// generic fallback (any N, any B) — the R2 kernel, 1 sample/thread
__global__ __launch_bounds__(256) void qnstep_td_generic(
    const float* __restrict__ q, const float* __restrict__ nq,
    const int* __restrict__ act, const int* __restrict__ nact,
    const float* __restrict__ rew, const int* __restrict__ done,
    const float* __restrict__ w, const float* __restrict__ gamma_p,
    float* __restrict__ out, float* __restrict__ partial,
    int B, int N, int T)
{
    const int b = blockIdx.x * blockDim.x + threadIdx.x;
    const float gamma = gamma_p[0];
    float val = 0.0f;
    if (b < B) {
        float f = 1.0f, tgt = 0.0f;
        for (int t = 0; t < T; ++t) { tgt += f * rew[(long long)t * B + b]; f *= gamma; }
        const float nd = (done[b] != 0) ? 0.f : 1.f;
        tgt += f * nq[(long long)b * N + nact[b]] * nd;
        const float d = q[(long long)b * N + act[b]] - tgt;
        const float td = d * d;
        out[1 + b] = td;
        val = td * w[b];
    }
    #pragma unroll
    for (int off = 32; off > 0; off >>= 1) val += __shfl_down(val, off, 64);
    __shared__ float ssum[4];
    if ((threadIdx.x & 63) == 0) ssum[threadIdx.x >> 6] = val;
    __syncthreads();
    if (threadIdx.x == 0)
        partial[blockIdx.x] = ssum[0] + ssum[1] + ssum[2] + ssum[3];
}

__global__ __launch_bounds__(1024) void qnstep_td_reduce(
    const float* __restrict__ partial, float* __restrict__ out,
    int n, float invB)
{
    const int tid = threadIdx.x;
    float v = 0.0f;
    for (int i = tid; i < n; i += 1024) v += partial[i];

    #pragma unroll
    for (int off = 32; off > 0; off >>= 1)
        v += __shfl_down(v, off, 64);

    __shared__ float ssum[16];
    if ((tid & 63) == 0) ssum[tid >> 6] = v;
    __syncthreads();

    if (tid == 0) {
        float s = 0.0f;
        #pragma unroll
        for (int i = 0; i < 16; ++i) s += ssum[i];
        out[0] = s * invB;  // overwrites poison
    }
}

extern "C" void kernel_launch(void* const* d_in, const int* in_sizes, int n_in,
                              void* d_out, int out_size, void* d_ws, size_t ws_size,
                              hipStream_t stream) {
    const float* q     = (const float*)d_in[0];
    const float* nq    = (const float*)d_in[1];
    const int*   act   = (const int*)d_in[2];
    const int*   nact  = (const int*)d_in[3];
    const float* rew   = (const float*)d_in[4];
    const int*   done  = (const int*)d_in[5];
    const float* w     = (const float*)d_in[6];
    const float* gamma = (const float*)d_in[7];

    const int B = in_sizes[2];            // action is (B,)
    const int N = in_sizes[0] / B;        // q is (B, N)
    const int T = in_sizes[4] / B;        // reward is (T, B)

    float* out     = (float*)d_out;
    float* partial = (float*)d_ws;

    if (N == 16 && (B % BLOCK) == 0) {
        const int grid = B / BLOCK;       // 4096 for B=1M
        qnstep_td_main<<<grid, BLOCK, 0, stream>>>(
            q, nq, act, nact, rew, done, w, gamma, out, partial, B, T);
        qnstep_td_reduce<<<1, 1024, 0, stream>>>(partial, out, grid, 1.0f / (float)B);
    } else {
        const int grid = (B + 255) / 256;
        qnstep_td_generic<<<grid, 256, 0, stream>>>(
            q, nq, act, nact, rew, done, w, gamma, out, partial, B, N, T);
        qnstep_td_reduce<<<1, 1024, 0, stream>>>(partial, out, grid, 1.0f / (float)B);
    }
}